// Round 13
// baseline (164.825 us; speedup 1.0000x reference)
//
#include <hip/hip_runtime.h>

#define DI __device__ __forceinline__

typedef __attribute__((ext_vector_type(8))) short short8;
typedef __attribute__((ext_vector_type(4))) float f32x4;

// ---------- helpers ----------
DI ushort f2bf(float f) {
  union { float f; unsigned u; } v; v.f = f;
  unsigned r = v.u + 0x7fffu + ((v.u >> 16) & 1u);
  return (ushort)(r >> 16);
}

DI void gload_lds16(const void* g, void* l) {
  __builtin_amdgcn_global_load_lds((const __attribute__((address_space(1))) void*)g,
                                   (__attribute__((address_space(3))) void*)l, 16, 0, 0);
}

// LESSONS:
// R6: don't fuse heterogeneous prep streams (BW collapse).
// R7/R10: splitK x4 / BK=32 variants regress vs splitK x2 / BK=64.
// R8: A-direct-to-register under (256,2) VGPR cap -> serialized loads.
// R11: lazyP scattered 2B stores were ~9us; coalesced 3-pass fixed it.
// R12: launch gaps ~1.5us each; fused b2->biW, invp->mix (-3us).
// R13: __syncthreads' vmcnt(0) drain is the gemm stall; counted vmcnt(6)
//      + raw s_barrier + 3-buffer 2-ahead prefetch (T4/m218 mechanism).

// ---------- 1. t = Pbm @ lb (512x512 matvec), one wave per output ----------
__global__ __launch_bounds__(256) void k_matvec(const float* __restrict__ A,
                                                const float* __restrict__ v,
                                                float* __restrict__ y) {
  int o = blockIdx.x * 4 + (threadIdx.x >> 6);
  int lane = threadIdx.x & 63;
  float acc = 0.f;
  for (int k = lane; k < 512; k += 64) acc += A[o * 512 + k] * v[k];
#pragma unroll
  for (int s = 32; s; s >>= 1) acc += __shfl_down(acc, s, 64);
  if (lane == 0) y[o] = acc;
}

// ---------- 2. M = I + 0.1*sum_w bi_w[w]*bi_basis[w]; b2 = M @ t fused -------
__global__ __launch_bounds__(256) void k_biW(const float2* __restrict__ bb,
                                             const float* __restrict__ bw,
                                             const float* __restrict__ tvec,
                                             float2* __restrict__ Mf32,
                                             uint* __restrict__ Mbf16,
                                             float* __restrict__ b2) {
  __shared__ float w[128];
  __shared__ float ps[4];
  int tid = threadIdx.x;
  if (tid < 128) w[tid] = bw[tid];
  __syncthreads();
  int t = blockIdx.x * 256 + tid;            // 131072 threads, 2 elems each
  const float2* p = bb + t;
  float ax = 0.f, ay = 0.f;
#pragma unroll 16
  for (int k = 0; k < 128; ++k) {
    float2 v = p[(size_t)k * 131072];
    float s = w[k];
    ax += s * v.x; ay += s * v.y;
  }
  int i = t >> 8, j0 = (t & 255) * 2;
  float2 r;
  r.x = 0.1f * ax + (i == j0 + 0 ? 1.f : 0.f);
  r.y = 0.1f * ay + (i == j0 + 1 ? 1.f : 0.f);
  Mf32[t] = r;
  Mbf16[t] = (uint)f2bf(r.x) | ((uint)f2bf(r.y) << 16);
  float2 tv = ((const float2*)tvec)[tid];
  float pr = r.x * tv.x + r.y * tv.y;
  int lane = tid & 63, wid = tid >> 6;
#pragma unroll
  for (int s = 32; s; s >>= 1) pr += __shfl_down(pr, s, 64);
  if (lane == 0) ps[wid] = pr;
  __syncthreads();
  if (tid == 0) b2[blockIdx.x] = ps[0] + ps[1] + ps[2] + ps[3];
}

// ---------- 3. fused invp + mix: invT scatter + Wmix[c][q] coalesced ---------
__global__ __launch_bounds__(256) void k_mix(const float* __restrict__ LW,
                                             const float* __restrict__ Pa,
                                             const float* __restrict__ Pb8,
                                             const int* __restrict__ perm,
                                             int* __restrict__ invT,
                                             ushort* __restrict__ Wmix) {
  int q = blockIdx.x * 256 + threadIdx.x;    // 262144 threads
  int lane = threadIdx.x & 63;
  int r = perm[q];
  int o = r >> 9, ic = r & 511;
  invT[ic * 512 + o] = q;
  int a_own = o * 4608 + ic;
  if (q < 131072) {                          // term a: s=4
    int ii = lane & 3, g = lane & ~3;
    float pp[4];
#pragma unroll
    for (int j = 0; j < 4; ++j) pp[j] = Pa[ii * 4 + j];
#pragma unroll
    for (int c = 0; c < 9; ++c) {
      float v = LW[a_own + c * 512];
      float acc = 0.f;
#pragma unroll
      for (int j = 0; j < 4; ++j) acc += pp[j] * __shfl(v, g + j, 64);
      Wmix[c * 262144 + q] = f2bf(acc);
    }
  } else {                                   // term b: s=8
    int ii = lane & 7, g = lane & ~7;
    float pp[8];
#pragma unroll
    for (int j = 0; j < 8; ++j) pp[j] = Pb8[ii * 8 + j];
#pragma unroll
    for (int c = 0; c < 9; ++c) {
      float v = LW[a_own + c * 512];
      float acc = 0.f;
#pragma unroll
      for (int j = 0; j < 8; ++j) acc += pp[j] * __shfl(v, g + j, 64);
      Wmix[c * 262144 + q] = f2bf(acc);
    }
  }
}

// ---------- 4. gather: Wt[(c*512+ic)*512+o] = Wmix[c][invT[ic*512+o]] --------
__global__ __launch_bounds__(256) void k_gather(const int* __restrict__ invT,
                                                const ushort* __restrict__ Wmix,
                                                ushort* __restrict__ Wt) {
  int gid = blockIdx.x * 256 + threadIdx.x;  // 294912 threads x 8 outputs
  int L = gid * 8;
  int c = L >> 18;
  int ic = (L >> 9) & 511;
  int o0 = L & 511;
  const int* ip = &invT[ic * 512 + o0];
  int4 qa = *(const int4*)ip;
  int4 qb = *(const int4*)(ip + 4);
  const ushort* wm = &Wmix[c * 262144];
  short8 v;
  v[0] = (short)wm[qa.x]; v[1] = (short)wm[qa.y];
  v[2] = (short)wm[qa.z]; v[3] = (short)wm[qa.w];
  v[4] = (short)wm[qb.x]; v[5] = (short)wm[qb.y];
  v[6] = (short)wm[qb.z]; v[7] = (short)wm[qb.w];
  *(short8*)&Wt[L] = v;
}

// ---------- 5. acts bf16 (8192 x 4608) ----------
__global__ __launch_bounds__(256) void k_acts(const float* __restrict__ x,
                                              const float* __restrict__ grid,
                                              const int* __restrict__ u,
                                              const int* __restrict__ indices,
                                              ushort* __restrict__ acts) {
  __shared__ float basis[8][64][9];
  __shared__ int sidx[512];
  int tid = threadIdx.x;
  int b0 = blockIdx.x * 8;
  for (int i = tid; i < 512; i += 256) sidx[i] = indices[i];
#pragma unroll
  for (int e0 = 0; e0 < 2; ++e0) {
    int e = e0 * 256 + tid;
    int row = e >> 6, j = e & 63;
    float gs = x[(size_t)(b0 + row) * 576 + u[j]];
    float g0 = grid[j * 6], g5 = grid[j * 6 + 5];
    float h = (g5 - g0) * 0.2f;
    float lo = g0 - 3.f * h;
    float tt = (gs - lo) / h;
#pragma unroll
    for (int n = 0; n < 8; ++n) basis[row][j][n] = 0.f;
    float fc = floorf(tt);
    int c = (int)fc;
    if (c >= 0 && c <= 10) {
      float t = tt - fc;
      float t2 = t * t, t3 = t2 * t;
      float om = 1.f - t;
      float w0 = t3 * (1.f / 6.f);
      float w1 = (1.f + 3.f * t + 3.f * t2 - 3.f * t3) * (1.f / 6.f);
      float w2 = (4.f - 6.f * t2 + 3.f * t3) * (1.f / 6.f);
      float w3 = om * om * om * (1.f / 6.f);
      if (c <= 7) basis[row][j][c] = w0;
      if (c >= 1 && c <= 8) basis[row][j][c - 1] = w1;
      if (c >= 2 && c <= 9) basis[row][j][c - 2] = w2;
      if (c >= 3) basis[row][j][c - 3] = w3;
    }
    basis[row][j][8] = gs / (1.f + __expf(-gs));   // silu
  }
  __syncthreads();
#pragma unroll
  for (int rep = 0; rep < 2; ++rep) {
    int e = rep * 256 + tid;
    int row = e >> 6, i0 = (e & 63) * 8;
    size_t xb = (size_t)(b0 + row) * 576;
    float4 xa = *(const float4*)&x[xb + i0];
    float4 xc = *(const float4*)&x[xb + i0 + 4];
    int4 ja = *(const int4*)&sidx[i0];
    int4 jb = *(const int4*)&sidx[i0 + 4];
    size_t ab = (size_t)(b0 + row) * 4608 + i0;
#pragma unroll
    for (int n = 0; n < 9; ++n) {
      short8 hv;
      hv[0] = (short)f2bf(basis[row][ja.x][n] * xa.x);
      hv[1] = (short)f2bf(basis[row][ja.y][n] * xa.y);
      hv[2] = (short)f2bf(basis[row][ja.z][n] * xa.z);
      hv[3] = (short)f2bf(basis[row][ja.w][n] * xa.w);
      hv[4] = (short)f2bf(basis[row][jb.x][n] * xc.x);
      hv[5] = (short)f2bf(basis[row][jb.y][n] * xc.y);
      hv[6] = (short)f2bf(basis[row][jb.z][n] * xc.z);
      hv[7] = (short)f2bf(basis[row][jb.w][n] * xc.w);
      *(short8*)(&acts[ab + (size_t)n * 512]) = hv;
    }
  }
}

// ---------- 6. W2 GEMM: C[m,n] = sum_k A[m,k]*B[n,k], bf16 out (BK=64) ------
template <int BM, int BN>
__global__ __launch_bounds__(256) void gemm_bt(const ushort* __restrict__ A,
                                               const ushort* __restrict__ B,
                                               ushort* __restrict__ Cout,
                                               int N, int Kd) {
  constexpr int BK = 64;
  constexpr int FM = BM / 32;
  constexpr int FN = BN / 32;
  __shared__ __align__(16) ushort Al[2][BM * BK];
  __shared__ __align__(16) ushort Bl[2][BN * BK];
  int tid = threadIdx.x, lane = tid & 63, wid = tid >> 6;
  int wm = wid >> 1, wn = wid & 1;
  int tiles_n = N / BN;
  int per_xcd = gridDim.x >> 3;
  int flat = (blockIdx.x & 7) * per_xcd + (blockIdx.x >> 3);
  int bm = flat / tiles_n, bn = flat % tiles_n;
  long m0 = (long)bm * BM;
  long n0 = (long)bn * BN;
  int swc = ((tid & 7) ^ ((tid >> 3) & 7)) * 8;
  const ushort* agp = A + (m0 + (tid >> 3)) * (long)Kd + swc;
  const ushort* bgp = B + (n0 + (tid >> 3)) * (long)Kd + swc;

#define STAGE64(buf, k0)                                                      \
  do {                                                                        \
    _Pragma("unroll")                                                         \
    for (int it = 0; it < BM / 32; ++it)                                      \
      gload_lds16(agp + (it * 32) * (long)Kd + (k0), &Al[buf][(it * 256 + tid) * 8]); \
    _Pragma("unroll")                                                         \
    for (int it = 0; it < BN / 32; ++it)                                      \
      gload_lds16(bgp + (it * 32) * (long)Kd + (k0), &Bl[buf][(it * 256 + tid) * 8]); \
  } while (0)

  f32x4 acc[FM][FN] = {};
  int swz = (lane & 7) << 3;
  int nt = Kd / BK;
  STAGE64(0, 0);
  __syncthreads();
  for (int t = 0; t < nt; ++t) {
    int cur = t & 1;
    if (t + 1 < nt) STAGE64(cur ^ 1, (t + 1) * BK);
#pragma unroll
    for (int ks = 0; ks < 2; ++ks) {
      int kidx = (ks * 32 + (lane >> 4) * 8) ^ swz;
      short8 a[FM], b[FN];
#pragma unroll
      for (int f = 0; f < FM; ++f)
        a[f] = *(const short8*)&Al[cur][(wm * (FM * 16) + f * 16 + (lane & 15)) * BK + kidx];
#pragma unroll
      for (int f = 0; f < FN; ++f)
        b[f] = *(const short8*)&Bl[cur][(wn * (FN * 16) + f * 16 + (lane & 15)) * BK + kidx];
#pragma unroll
      for (int i = 0; i < FM; ++i)
#pragma unroll
        for (int j = 0; j < FN; ++j)
          acc[i][j] = __builtin_amdgcn_mfma_f32_16x16x32_bf16(a[i], b[j], acc[i][j], 0, 0, 0);
    }
    __syncthreads();
  }
#undef STAGE64
#pragma unroll
  for (int i = 0; i < FM; ++i)
#pragma unroll
    for (int j = 0; j < FN; ++j) {
      int row_b = wm * (FM * 16) + i * 16 + ((lane >> 4) * 4);
      long col = n0 + wn * (FN * 16) + j * 16 + (lane & 15);
#pragma unroll
      for (int r = 0; r < 4; ++r)
        Cout[(m0 + row_b + r) * N + col] = f2bf(acc[i][j][r]);
    }
}

// ---------- 7. main GEMM: 256x128 tile, 8 waves (4Mx2N), split-K x2,
// TRIPLE-buffered LDS (144KB, 1 blk/CU), 2-tiles-ahead prefetch, counted
// s_waitcnt vmcnt(6) + raw s_barrier (loads stay in flight across barriers —
// T4/m218 mechanism; __syncthreads' vmcnt(0) drain was the stall).
// Safety: one barrier per K-tile orders both "buf[cur] fully written" (each
// wave waits its own 6 tile-t loads via vmcnt(6); barrier joins all) and
// "buf[stage] free" (all waves' ds_reads of it finished before the barrier).
__global__ __launch_bounds__(512, 1) void gemm_sk(const ushort* __restrict__ A,
                                                  const ushort* __restrict__ B,
                                                  const float* __restrict__ b2,
                                                  float* __restrict__ P0,
                                                  float* __restrict__ P1) {
  constexpr int BK = 64, FM = 4, FN = 4;
  const int Kd = 4608, N = 512;
  __shared__ __align__(16) ushort Al[3][256 * BK];   // 3 x 32 KB
  __shared__ __align__(16) ushort Bl[3][128 * BK];   // 3 x 16 KB
  int tid = threadIdx.x;                    // 0..511
  int lane = tid & 63, wid = tid >> 6;      // 8 waves
  int wm = wid >> 1, wn = wid & 1;          // 4M x 2N
  // grid 256: per_xcd = 32; flat = bm[3..7]|kb[2]|bn[0..1]
  int flat = (blockIdx.x & 7) * 32 + (blockIdx.x >> 3);
  int bm = flat >> 3, kb = (flat >> 2) & 1, bn = flat & 3;
  long m0 = (long)bm * 256, n0 = (long)bn * 128;
  int kbase = kb * 2304;
  float* Pout = kb ? P1 : P0;

  // staging: 512 thr; A: 4 its x (64 rows), B: 2 its; chunk c = tid&7,
  // row = tid>>3 (+64/it, preserves &7) -> source pre-swizzle (rule #21).
  int swc = ((tid & 7) ^ ((tid >> 3) & 7)) * 8;
  const ushort* agp = A + (m0 + (tid >> 3)) * (long)Kd + kbase + swc;
  const ushort* bgp = B + (n0 + (tid >> 3)) * (long)Kd + kbase + swc;

#define STAGE_A2(buf, k0, it0)                                                \
  do {                                                                        \
    gload_lds16(agp + ((it0) * 64) * (long)Kd + (k0), &Al[buf][((it0) * 512 + tid) * 8]);       \
    gload_lds16(agp + ((it0 + 1) * 64) * (long)Kd + (k0), &Al[buf][((it0 + 1) * 512 + tid) * 8]); \
  } while (0)
#define STAGE_B2(buf, k0)                                                     \
  do {                                                                        \
    gload_lds16(bgp + 0 * (long)Kd + (k0), &Bl[buf][(0 * 512 + tid) * 8]);    \
    gload_lds16(bgp + 64 * (long)Kd + (k0), &Bl[buf][(1 * 512 + tid) * 8]);   \
  } while (0)
#define STAGE_ALL(buf, k0) do { STAGE_A2(buf, k0, 0); STAGE_A2(buf, k0, 2); STAGE_B2(buf, k0); } while (0)

  f32x4 acc[FM][FN] = {};
  int swz = (lane & 7) << 3;
  const int nt = 2304 / BK;                 // 36
  STAGE_ALL(0, 0);                          // tile 0 (6 loads)
  STAGE_ALL(1, BK);                         // tile 1 (6 loads)
  for (int t = 0; t < nt; ++t) {
    int cur = t % 3;
    int stg = (t + 2) % 3;
    // wait own tile-t loads (6 newer stay in flight), then join all waves
    if (t < nt - 1) asm volatile("s_waitcnt vmcnt(6)" ::: "memory");
    else            asm volatile("s_waitcnt vmcnt(0)" ::: "memory");
    __builtin_amdgcn_s_barrier();
    bool st = (t + 2) < nt;
    // 4 phases = C-quadrants; per phase: 8 ds_read + <=2 staging + 8 MFMA
#pragma unroll
    for (int p = 0; p < 4; ++p) {
      int qi = (p >> 1) * 2, qj = (p & 1) * 2;   // frag-quadrant base
      short8 a[2][2], b[2][2];                   // [ks][f]
#pragma unroll
      for (int ks = 0; ks < 2; ++ks) {
        int kidx = (ks * 32 + (lane >> 4) * 8) ^ swz;
#pragma unroll
        for (int f = 0; f < 2; ++f) {
          a[ks][f] = *(const short8*)&Al[cur][(wm * 64 + (qi + f) * 16 + (lane & 15)) * BK + kidx];
          b[ks][f] = *(const short8*)&Bl[cur][(wn * 64 + (qj + f) * 16 + (lane & 15)) * BK + kidx];
        }
      }
      if (st) {
        long k0 = (long)(t + 2) * BK;
        if (p == 0) STAGE_A2(stg, k0, 0);
        else if (p == 1) STAGE_A2(stg, k0, 2);
        else if (p == 2) STAGE_B2(stg, k0);
      }
      __builtin_amdgcn_s_setprio(1);
#pragma unroll
      for (int ks = 0; ks < 2; ++ks)
#pragma unroll
        for (int i = 0; i < 2; ++i)
#pragma unroll
          for (int j = 0; j < 2; ++j)
            acc[qi + i][qj + j] = __builtin_amdgcn_mfma_f32_16x16x32_bf16(
                a[ks][i], b[ks][j], acc[qi + i][qj + j], 0, 0, 0);
      __builtin_amdgcn_s_setprio(0);
    }
  }
#undef STAGE_A2
#undef STAGE_B2
#undef STAGE_ALL
#pragma unroll
  for (int i = 0; i < FM; ++i)
#pragma unroll
    for (int j = 0; j < FN; ++j) {
      int row_b = wm * 64 + i * 16 + ((lane >> 4) * 4);
      long col = n0 + wn * 64 + j * 16 + (lane & 15);
      float bv = (kb == 0) ? b2[col] : 0.f;
#pragma unroll
      for (int r = 0; r < 4; ++r)
        Pout[(m0 + row_b + r) * N + col] = acc[i][j][r] + bv;
    }
}

// ---------- 8. out = P0 + P1 (f32, in-place on P0 = d_out) ----------
__global__ __launch_bounds__(256) void k_reduce(float4* __restrict__ P0,
                                                const float4* __restrict__ P1) {
  int t = blockIdx.x * 256 + threadIdx.x;
#pragma unroll
  for (int rep = 0; rep < 2; ++rep) {
    int e = rep * 524288 + t;
    float4 a = P0[e], b = P1[e];
    a.x += b.x; a.y += b.y; a.z += b.z; a.w += b.w;
    P0[e] = a;
  }
}

// ---------- launch ----------
extern "C" void kernel_launch(void* const* d_in, const int* in_sizes, int n_in,
                              void* d_out, int out_size, void* d_ws, size_t ws_size,
                              hipStream_t stream) {
  const float* x        = (const float*)d_in[0];
  const float* grid     = (const float*)d_in[1];
  const float* LW       = (const float*)d_in[2];
  const float* lb       = (const float*)d_in[3];
  const float* Pa       = (const float*)d_in[4];
  const float* Pb8      = (const float*)d_in[5];
  const float* Pbm      = (const float*)d_in[6];
  const float* bi_basis = (const float*)d_in[7];
  const float* bi_w     = (const float*)d_in[8];
  const int*   u        = (const int*)d_in[9];
  const int*   indices  = (const int*)d_in[10];
  const int*   perm     = (const int*)d_in[11];
  float* out = (float*)d_out;
  char* ws = (char*)d_ws;

  float*  Mf32  = (float*)(ws + 0);               // 1 MB
  ushort* Mbf16 = (ushort*)(ws + 1048576);        // 0.5 MB
  float*  tvec  = (float*)(ws + 1572864);         // 2 KB
  float*  b2    = (float*)(ws + 1576960);         // 2 KB
  ushort* Wt    = (ushort*)(ws + 2097152);        // 4.5 MB   (4608 x 512 bf16)
  ushort* W2    = (ushort*)(ws + 6815744);        // 4.5 MB   (512 x 4608 bf16)
  ushort* acts  = (ushort*)(ws + 11534336);       // 72 MB    (8192 x 4608 bf16)
  float*  P1    = (float*)(ws + 87031808);        // 16 MB    (split-K partial)
  int*    invT  = (int*)(ws + 103809024);         // 1 MB
  ushort* Wmix  = (ushort*)(ws + 104857600);      // 4.5 MB   (9 x 262144 bf16)

  // 1. t = Pbm @ lb
  k_matvec<<<128, 256, 0, stream>>>(Pbm, lb, tvec);
  // 2. M = I + 0.1*bi_w.bi_basis ; b2 = M @ t (fused)
  k_biW<<<512, 256, 0, stream>>>((const float2*)bi_basis, bi_w, tvec,
                                 (float2*)Mf32, (uint*)Mbf16, b2);
  // 3. fused invp + mix
  k_mix<<<1024, 256, 0, stream>>>(LW, Pa, Pb8, perm, invT, Wmix);
  // 4. gather -> Wt
  k_gather<<<1152, 256, 0, stream>>>(invT, Wmix, Wt);
  // 5. W2 = M @ Wt^T  (grid 288)
  gemm_bt<64, 128><<<(512 / 64) * (4608 / 128), 256, 0, stream>>>(
      Mbf16, Wt, W2, 4608, 512);
  // 6. acts
  k_acts<<<1024, 256, 0, stream>>>(x, grid, u, indices, acts);
  // 7. main GEMM: 256 blocks x 512 threads, counted-vmcnt pipeline
  gemm_sk<<<256, 512, 0, stream>>>(acts, W2, b2, out, P1);
  // 8. out = P0 + P1
  k_reduce<<<2048, 256, 0, stream>>>((float4*)out, (const float4*)P1);
}

// Round 14
// 154.743 us; speedup vs baseline: 1.0652x; 1.0652x over previous
//
#include <hip/hip_runtime.h>

#define DI __device__ __forceinline__

typedef __attribute__((ext_vector_type(8))) short short8;
typedef __attribute__((ext_vector_type(4))) float f32x4;

// ---------- helpers ----------
DI ushort f2bf(float f) {
  union { float f; unsigned u; } v; v.f = f;
  unsigned r = v.u + 0x7fffu + ((v.u >> 16) & 1u);
  return (ushort)(r >> 16);
}

DI void gload_lds16(const void* g, void* l) {
  __builtin_amdgcn_global_load_lds((const __attribute__((address_space(1))) void*)g,
                                   (__attribute__((address_space(3))) void*)l, 16, 0, 0);
}

// LESSONS (final):
// R6: don't fuse heterogeneous prep streams (BW collapse).
// R3/R7/R8/R10/R13: five GEMM restructures (dbuf-2ph, splitKx4/BK32,
//   A-in-reg, wave-tile 128x64, counted-vmcnt 256x128) all regressed vs the
//   plain splitKx2/BK=64/128^2/2blk-CU structure -> local optimum for this
//   shape; further gain needs the full 8-phase 256^2 template, not retrofits.
// R11: lazyP scattered 2B stores were ~9us; coalesced 3-pass fixed it.
// R12: launch gaps ~1.5us each; fused b2->biW, invp->mix. BEST = 155.9us.

// ---------- 1. t = Pbm @ lb (512x512 matvec), one wave per output ----------
__global__ __launch_bounds__(256) void k_matvec(const float* __restrict__ A,
                                                const float* __restrict__ v,
                                                float* __restrict__ y) {
  int o = blockIdx.x * 4 + (threadIdx.x >> 6);
  int lane = threadIdx.x & 63;
  float acc = 0.f;
  for (int k = lane; k < 512; k += 64) acc += A[o * 512 + k] * v[k];
#pragma unroll
  for (int s = 32; s; s >>= 1) acc += __shfl_down(acc, s, 64);
  if (lane == 0) y[o] = acc;
}

// ---------- 2. M = I + 0.1*sum_w bi_w[w]*bi_basis[w]; b2 = M @ t fused -------
// Block bid covers exactly row i=bid, so b2[i] is a free block-reduction.
__global__ __launch_bounds__(256) void k_biW(const float2* __restrict__ bb,
                                             const float* __restrict__ bw,
                                             const float* __restrict__ tvec,
                                             float2* __restrict__ Mf32,
                                             uint* __restrict__ Mbf16,
                                             float* __restrict__ b2) {
  __shared__ float w[128];
  __shared__ float ps[4];
  int tid = threadIdx.x;
  if (tid < 128) w[tid] = bw[tid];
  __syncthreads();
  int t = blockIdx.x * 256 + tid;            // 131072 threads, 2 elems each
  const float2* p = bb + t;
  float ax = 0.f, ay = 0.f;
#pragma unroll 16
  for (int k = 0; k < 128; ++k) {
    float2 v = p[(size_t)k * 131072];
    float s = w[k];
    ax += s * v.x; ay += s * v.y;
  }
  int i = t >> 8, j0 = (t & 255) * 2;
  float2 r;
  r.x = 0.1f * ax + (i == j0 + 0 ? 1.f : 0.f);
  r.y = 0.1f * ay + (i == j0 + 1 ? 1.f : 0.f);
  Mf32[t] = r;
  Mbf16[t] = (uint)f2bf(r.x) | ((uint)f2bf(r.y) << 16);
  // b2[i] = sum_j M[i][j] * t[j]
  float2 tv = ((const float2*)tvec)[tid];
  float pr = r.x * tv.x + r.y * tv.y;
  int lane = tid & 63, wid = tid >> 6;
#pragma unroll
  for (int s = 32; s; s >>= 1) pr += __shfl_down(pr, s, 64);
  if (lane == 0) ps[wid] = pr;
  __syncthreads();
  if (tid == 0) b2[blockIdx.x] = ps[0] + ps[1] + ps[2] + ps[3];
}

// ---------- 3. fused invp + mix: invT scatter + Wmix[c][q] coalesced ---------
__global__ __launch_bounds__(256) void k_mix(const float* __restrict__ LW,
                                             const float* __restrict__ Pa,
                                             const float* __restrict__ Pb8,
                                             const int* __restrict__ perm,
                                             int* __restrict__ invT,
                                             ushort* __restrict__ Wmix) {
  int q = blockIdx.x * 256 + threadIdx.x;    // 262144 threads
  int lane = threadIdx.x & 63;
  int r = perm[q];
  int o = r >> 9, ic = r & 511;
  invT[ic * 512 + o] = q;                    // transposed inverse perm (4B x1)
  int a_own = o * 4608 + ic;
  if (q < 131072) {                          // term a: s=4, groups of 4 lanes
    int ii = lane & 3, g = lane & ~3;
    float pp[4];
#pragma unroll
    for (int j = 0; j < 4; ++j) pp[j] = Pa[ii * 4 + j];
#pragma unroll
    for (int c = 0; c < 9; ++c) {
      float v = LW[a_own + c * 512];
      float acc = 0.f;
#pragma unroll
      for (int j = 0; j < 4; ++j) acc += pp[j] * __shfl(v, g + j, 64);
      Wmix[c * 262144 + q] = f2bf(acc);
    }
  } else {                                   // term b: s=8, groups of 8 lanes
    int ii = lane & 7, g = lane & ~7;
    float pp[8];
#pragma unroll
    for (int j = 0; j < 8; ++j) pp[j] = Pb8[ii * 8 + j];
#pragma unroll
    for (int c = 0; c < 9; ++c) {
      float v = LW[a_own + c * 512];
      float acc = 0.f;
#pragma unroll
      for (int j = 0; j < 8; ++j) acc += pp[j] * __shfl(v, g + j, 64);
      Wmix[c * 262144 + q] = f2bf(acc);
    }
  }
}

// ---------- 4. gather: Wt[(c*512+ic)*512+o] = Wmix[c][invT[ic*512+o]] --------
__global__ __launch_bounds__(256) void k_gather(const int* __restrict__ invT,
                                                const ushort* __restrict__ Wmix,
                                                ushort* __restrict__ Wt) {
  int gid = blockIdx.x * 256 + threadIdx.x;  // 294912 threads x 8 outputs
  int L = gid * 8;
  int c = L >> 18;
  int ic = (L >> 9) & 511;
  int o0 = L & 511;
  const int* ip = &invT[ic * 512 + o0];
  int4 qa = *(const int4*)ip;
  int4 qb = *(const int4*)(ip + 4);
  const ushort* wm = &Wmix[c * 262144];
  short8 v;
  v[0] = (short)wm[qa.x]; v[1] = (short)wm[qa.y];
  v[2] = (short)wm[qa.z]; v[3] = (short)wm[qa.w];
  v[4] = (short)wm[qb.x]; v[5] = (short)wm[qb.y];
  v[6] = (short)wm[qb.z]; v[7] = (short)wm[qb.w];
  *(short8*)&Wt[L] = v;
}

// ---------- 5. acts bf16 (8192 x 4608) ----------
__global__ __launch_bounds__(256) void k_acts(const float* __restrict__ x,
                                              const float* __restrict__ grid,
                                              const int* __restrict__ u,
                                              const int* __restrict__ indices,
                                              ushort* __restrict__ acts) {
  __shared__ float basis[8][64][9];
  __shared__ int sidx[512];
  int tid = threadIdx.x;
  int b0 = blockIdx.x * 8;
  for (int i = tid; i < 512; i += 256) sidx[i] = indices[i];
#pragma unroll
  for (int e0 = 0; e0 < 2; ++e0) {
    int e = e0 * 256 + tid;
    int row = e >> 6, j = e & 63;
    float gs = x[(size_t)(b0 + row) * 576 + u[j]];
    float g0 = grid[j * 6], g5 = grid[j * 6 + 5];
    float h = (g5 - g0) * 0.2f;
    float lo = g0 - 3.f * h;
    float tt = (gs - lo) / h;
#pragma unroll
    for (int n = 0; n < 8; ++n) basis[row][j][n] = 0.f;
    float fc = floorf(tt);
    int c = (int)fc;
    if (c >= 0 && c <= 10) {
      float t = tt - fc;
      float t2 = t * t, t3 = t2 * t;
      float om = 1.f - t;
      float w0 = t3 * (1.f / 6.f);
      float w1 = (1.f + 3.f * t + 3.f * t2 - 3.f * t3) * (1.f / 6.f);
      float w2 = (4.f - 6.f * t2 + 3.f * t3) * (1.f / 6.f);
      float w3 = om * om * om * (1.f / 6.f);
      if (c <= 7) basis[row][j][c] = w0;
      if (c >= 1 && c <= 8) basis[row][j][c - 1] = w1;
      if (c >= 2 && c <= 9) basis[row][j][c - 2] = w2;
      if (c >= 3) basis[row][j][c - 3] = w3;
    }
    basis[row][j][8] = gs / (1.f + __expf(-gs));   // silu
  }
  __syncthreads();
#pragma unroll
  for (int rep = 0; rep < 2; ++rep) {
    int e = rep * 256 + tid;
    int row = e >> 6, i0 = (e & 63) * 8;
    size_t xb = (size_t)(b0 + row) * 576;
    float4 xa = *(const float4*)&x[xb + i0];
    float4 xc = *(const float4*)&x[xb + i0 + 4];
    int4 ja = *(const int4*)&sidx[i0];
    int4 jb = *(const int4*)&sidx[i0 + 4];
    size_t ab = (size_t)(b0 + row) * 4608 + i0;
#pragma unroll
    for (int n = 0; n < 9; ++n) {
      short8 hv;
      hv[0] = (short)f2bf(basis[row][ja.x][n] * xa.x);
      hv[1] = (short)f2bf(basis[row][ja.y][n] * xa.y);
      hv[2] = (short)f2bf(basis[row][ja.z][n] * xa.z);
      hv[3] = (short)f2bf(basis[row][ja.w][n] * xa.w);
      hv[4] = (short)f2bf(basis[row][jb.x][n] * xc.x);
      hv[5] = (short)f2bf(basis[row][jb.y][n] * xc.y);
      hv[6] = (short)f2bf(basis[row][jb.z][n] * xc.z);
      hv[7] = (short)f2bf(basis[row][jb.w][n] * xc.w);
      *(short8*)(&acts[ab + (size_t)n * 512]) = hv;
    }
  }
}

// ---------- 6. W2 GEMM: C[m,n] = sum_k A[m,k]*B[n,k], bf16 out (BK=64) ------
template <int BM, int BN>
__global__ __launch_bounds__(256) void gemm_bt(const ushort* __restrict__ A,
                                               const ushort* __restrict__ B,
                                               ushort* __restrict__ Cout,
                                               int N, int Kd) {
  constexpr int BK = 64;
  constexpr int FM = BM / 32;
  constexpr int FN = BN / 32;
  __shared__ __align__(16) ushort Al[2][BM * BK];
  __shared__ __align__(16) ushort Bl[2][BN * BK];
  int tid = threadIdx.x, lane = tid & 63, wid = tid >> 6;
  int wm = wid >> 1, wn = wid & 1;
  int tiles_n = N / BN;
  int per_xcd = gridDim.x >> 3;
  int flat = (blockIdx.x & 7) * per_xcd + (blockIdx.x >> 3);
  int bm = flat / tiles_n, bn = flat % tiles_n;
  long m0 = (long)bm * BM;
  long n0 = (long)bn * BN;
  int swc = ((tid & 7) ^ ((tid >> 3) & 7)) * 8;
  const ushort* agp = A + (m0 + (tid >> 3)) * (long)Kd + swc;
  const ushort* bgp = B + (n0 + (tid >> 3)) * (long)Kd + swc;

#define STAGE64(buf, k0)                                                      \
  do {                                                                        \
    _Pragma("unroll")                                                         \
    for (int it = 0; it < BM / 32; ++it)                                      \
      gload_lds16(agp + (it * 32) * (long)Kd + (k0), &Al[buf][(it * 256 + tid) * 8]); \
    _Pragma("unroll")                                                         \
    for (int it = 0; it < BN / 32; ++it)                                      \
      gload_lds16(bgp + (it * 32) * (long)Kd + (k0), &Bl[buf][(it * 256 + tid) * 8]); \
  } while (0)

  f32x4 acc[FM][FN] = {};
  int swz = (lane & 7) << 3;
  int nt = Kd / BK;
  STAGE64(0, 0);
  __syncthreads();
  for (int t = 0; t < nt; ++t) {
    int cur = t & 1;
    if (t + 1 < nt) STAGE64(cur ^ 1, (t + 1) * BK);
#pragma unroll
    for (int ks = 0; ks < 2; ++ks) {
      int kidx = (ks * 32 + (lane >> 4) * 8) ^ swz;
      short8 a[FM], b[FN];
#pragma unroll
      for (int f = 0; f < FM; ++f)
        a[f] = *(const short8*)&Al[cur][(wm * (FM * 16) + f * 16 + (lane & 15)) * BK + kidx];
#pragma unroll
      for (int f = 0; f < FN; ++f)
        b[f] = *(const short8*)&Bl[cur][(wn * (FN * 16) + f * 16 + (lane & 15)) * BK + kidx];
#pragma unroll
      for (int i = 0; i < FM; ++i)
#pragma unroll
        for (int j = 0; j < FN; ++j)
          acc[i][j] = __builtin_amdgcn_mfma_f32_16x16x32_bf16(a[i], b[j], acc[i][j], 0, 0, 0);
    }
    __syncthreads();
  }
#undef STAGE64
#pragma unroll
  for (int i = 0; i < FM; ++i)
#pragma unroll
    for (int j = 0; j < FN; ++j) {
      int row_b = wm * (FM * 16) + i * 16 + ((lane >> 4) * 4);
      long col = n0 + wn * (FN * 16) + j * 16 + (lane & 15);
#pragma unroll
      for (int r = 0; r < 4; ++r)
        Cout[(m0 + row_b + r) * N + col] = f2bf(acc[i][j][r]);
    }
}

// ---------- 7. main GEMM, split-K x2, BK=64, A+B in LDS (R5 known-good) ------
__global__ __launch_bounds__(256, 2) void gemm_sk(const ushort* __restrict__ A,
                                                  const ushort* __restrict__ B,
                                                  const float* __restrict__ b2,
                                                  float* __restrict__ P0,
                                                  float* __restrict__ P1) {
  constexpr int BM = 128, BN = 128, BK = 64, FM = 4, FN = 4;
  const int Kd = 4608, N = 512;
  __shared__ __align__(16) ushort Al[2][BM * BK];
  __shared__ __align__(16) ushort Bl[2][BN * BK];
  int tid = threadIdx.x, lane = tid & 63, wid = tid >> 6;
  int wm = wid >> 1, wn = wid & 1;
  int flat = (blockIdx.x & 7) * 64 + (blockIdx.x >> 3);
  int bm = flat >> 3, kb = (flat >> 2) & 1, bn = flat & 3;
  long m0 = (long)bm * BM, n0 = (long)bn * BN;
  int kbase = kb * 2304;
  float* Pout = kb ? P1 : P0;

  int swc = ((tid & 7) ^ ((tid >> 3) & 7)) * 8;
  const ushort* agp = A + (m0 + (tid >> 3)) * (long)Kd + kbase + swc;
  const ushort* bgp = B + (n0 + (tid >> 3)) * (long)Kd + kbase + swc;

#define STAGE(buf, k0)                                                        \
  do {                                                                        \
    _Pragma("unroll")                                                         \
    for (int it = 0; it < 4; ++it)                                            \
      gload_lds16(agp + (it * 32) * (long)Kd + (k0), &Al[buf][(it * 256 + tid) * 8]); \
    _Pragma("unroll")                                                         \
    for (int it = 0; it < 4; ++it)                                            \
      gload_lds16(bgp + (it * 32) * (long)Kd + (k0), &Bl[buf][(it * 256 + tid) * 8]); \
  } while (0)

  f32x4 acc[FM][FN] = {};
  int swz = (lane & 7) << 3;
  const int nt = 2304 / BK;                        // 36
  STAGE(0, 0);
  __syncthreads();
  for (int t = 0; t < nt; ++t) {
    int cur = t & 1;
    if (t + 1 < nt) STAGE(cur ^ 1, (t + 1) * BK);
#pragma unroll
    for (int ks = 0; ks < 2; ++ks) {
      int kidx = (ks * 32 + (lane >> 4) * 8) ^ swz;
      short8 a[FM], b[FN];
#pragma unroll
      for (int f = 0; f < FM; ++f)
        a[f] = *(const short8*)&Al[cur][(wm * 64 + f * 16 + (lane & 15)) * BK + kidx];
#pragma unroll
      for (int f = 0; f < FN; ++f)
        b[f] = *(const short8*)&Bl[cur][(wn * 64 + f * 16 + (lane & 15)) * BK + kidx];
#pragma unroll
      for (int i = 0; i < FM; ++i)
#pragma unroll
        for (int j = 0; j < FN; ++j)
          acc[i][j] = __builtin_amdgcn_mfma_f32_16x16x32_bf16(a[i], b[j], acc[i][j], 0, 0, 0);
    }
    __syncthreads();
  }
#undef STAGE
#pragma unroll
  for (int i = 0; i < FM; ++i)
#pragma unroll
    for (int j = 0; j < FN; ++j) {
      int row_b = wm * 64 + i * 16 + ((lane >> 4) * 4);
      long col = n0 + wn * 64 + j * 16 + (lane & 15);
      float bv = (kb == 0) ? b2[col] : 0.f;
#pragma unroll
      for (int r = 0; r < 4; ++r)
        Pout[(m0 + row_b + r) * N + col] = acc[i][j][r] + bv;
    }
}

// ---------- 8. out = P0 + P1 (f32, in-place on P0 = d_out) ----------
__global__ __launch_bounds__(256) void k_reduce(float4* __restrict__ P0,
                                                const float4* __restrict__ P1) {
  int t = blockIdx.x * 256 + threadIdx.x;
#pragma unroll
  for (int rep = 0; rep < 2; ++rep) {
    int e = rep * 524288 + t;
    float4 a = P0[e], b = P1[e];
    a.x += b.x; a.y += b.y; a.z += b.z; a.w += b.w;
    P0[e] = a;
  }
}

// ---------- launch ----------
extern "C" void kernel_launch(void* const* d_in, const int* in_sizes, int n_in,
                              void* d_out, int out_size, void* d_ws, size_t ws_size,
                              hipStream_t stream) {
  const float* x        = (const float*)d_in[0];
  const float* grid     = (const float*)d_in[1];
  const float* LW       = (const float*)d_in[2];
  const float* lb       = (const float*)d_in[3];
  const float* Pa       = (const float*)d_in[4];
  const float* Pb8      = (const float*)d_in[5];
  const float* Pbm      = (const float*)d_in[6];
  const float* bi_basis = (const float*)d_in[7];
  const float* bi_w     = (const float*)d_in[8];
  const int*   u        = (const int*)d_in[9];
  const int*   indices  = (const int*)d_in[10];
  const int*   perm     = (const int*)d_in[11];
  float* out = (float*)d_out;
  char* ws = (char*)d_ws;

  float*  Mf32  = (float*)(ws + 0);               // 1 MB
  ushort* Mbf16 = (ushort*)(ws + 1048576);        // 0.5 MB
  float*  tvec  = (float*)(ws + 1572864);         // 2 KB
  float*  b2    = (float*)(ws + 1576960);         // 2 KB
  ushort* Wt    = (ushort*)(ws + 2097152);        // 4.5 MB   (4608 x 512 bf16)
  ushort* W2    = (ushort*)(ws + 6815744);        // 4.5 MB   (512 x 4608 bf16)
  ushort* acts  = (ushort*)(ws + 11534336);       // 72 MB    (8192 x 4608 bf16)
  float*  P1    = (float*)(ws + 87031808);        // 16 MB    (split-K partial)
  int*    invT  = (int*)(ws + 103809024);         // 1 MB
  ushort* Wmix  = (ushort*)(ws + 104857600);      // 4.5 MB   (9 x 262144 bf16)

  // 1. t = Pbm @ lb (independent of everything else -> first)
  k_matvec<<<128, 256, 0, stream>>>(Pbm, lb, tvec);
  // 2. M = I + 0.1*bi_w.bi_basis ; b2 = M @ t (fused block-reduction)
  k_biW<<<512, 256, 0, stream>>>((const float2*)bi_basis, bi_w, tvec,
                                 (float2*)Mf32, (uint*)Mbf16, b2);
  // 3. fused invp + mix
  k_mix<<<1024, 256, 0, stream>>>(LW, Pa, Pb8, perm, invT, Wmix);
  // 4. gather -> Wt
  k_gather<<<1152, 256, 0, stream>>>(invT, Wmix, Wt);
  // 5. W2[o,c] = sum_k M[o,k] * Wt[c,k]  (M=512, N=4608, K=512), grid 288
  gemm_bt<64, 128><<<(512 / 64) * (4608 / 128), 256, 0, stream>>>(
      Mbf16, Wt, W2, 4608, 512);
  // 6. acts
  k_acts<<<1024, 256, 0, stream>>>(x, grid, u, indices, acts);
  // 7. main GEMM split-K x2 (grid 512, 2 blk/CU); kb==0 adds b2
  gemm_sk<<<512, 256, 0, stream>>>(acts, W2, b2, out, P1);
  // 8. out = P0 + P1
  k_reduce<<<2048, 256, 0, stream>>>((float4*)out, (const float4*)P1);
}